// Round 8
// baseline (192.424 us; speedup 1.0000x reference)
//
#include <hip/hip_runtime.h>
#include <cmath>
#include <cstdint>

// ---------------------------------------------------------------------------
// unif_vMF: JAX Threefry-2x32 replication (PARTITIONABLE semantics).
// R8: R7 with the DPP ctrl as a template constant (compile fix).
//     (1) fused mu+wood heterogeneous launch; (2) vec butterfly stages
//     1/2/4/8 on VALU DPP adds; (3) device rotl via v_alignbit.
//
// Outputs (flat concat in d_out, all f32):
//   vecs [4*65536*128] | kld [65536] | mu [65536*128] | redundant_norm [65536]
// Workspace: w[262144] f32 | nwn[262144] f32 | Bhi[65536] f16 | Blo[65536] f16
// ---------------------------------------------------------------------------

#define BTOT 65536
#define NSAMP 4
#define HID 512
#define LATD 128
#define NW 262144u      /* NSAMP*BTOT */

typedef _Float16 half8 __attribute__((ext_vector_type(8)));
typedef _Float16 half4 __attribute__((ext_vector_type(4)));
typedef float f32x4 __attribute__((ext_vector_type(4)));

__host__ __device__ __forceinline__ uint32_t rotl32(uint32_t v, int r){
#if defined(__HIP_DEVICE_COMPILE__)
  return __builtin_amdgcn_alignbit(v, v, 32 - r);   // 1-op rotate
#else
  return (v << r) | (v >> (32 - r));
#endif
}

// Threefry-2x32, 20 rounds, JAX's schedule.
__host__ __device__ __forceinline__ void tf2(uint32_t k0, uint32_t k1,
                                             uint32_t x0, uint32_t x1,
                                             uint32_t& o0, uint32_t& o1){
  uint32_t ks2 = k0 ^ k1 ^ 0x1BD11BDAu;
  x0 += k0; x1 += k1;
  x0+=x1; x1=rotl32(x1,13); x1^=x0;
  x0+=x1; x1=rotl32(x1,15); x1^=x0;
  x0+=x1; x1=rotl32(x1,26); x1^=x0;
  x0+=x1; x1=rotl32(x1, 6); x1^=x0;
  x0+=k1; x1+=ks2+1u;
  x0+=x1; x1=rotl32(x1,17); x1^=x0;
  x0+=x1; x1=rotl32(x1,29); x1^=x0;
  x0+=x1; x1=rotl32(x1,16); x1^=x0;
  x0+=x1; x1=rotl32(x1,24); x1^=x0;
  x0+=ks2; x1+=k0+2u;
  x0+=x1; x1=rotl32(x1,13); x1^=x0;
  x0+=x1; x1=rotl32(x1,15); x1^=x0;
  x0+=x1; x1=rotl32(x1,26); x1^=x0;
  x0+=x1; x1=rotl32(x1, 6); x1^=x0;
  x0+=k0; x1+=k1+3u;
  x0+=x1; x1=rotl32(x1,17); x1^=x0;
  x0+=x1; x1=rotl32(x1,29); x1^=x0;
  x0+=x1; x1=rotl32(x1,16); x1^=x0;
  x0+=x1; x1=rotl32(x1,24); x1^=x0;
  x0+=k1; x1+=ks2+4u;
  x0+=x1; x1=rotl32(x1,13); x1^=x0;
  x0+=x1; x1=rotl32(x1,15); x1^=x0;
  x0+=x1; x1=rotl32(x1,26); x1^=x0;
  x0+=x1; x1=rotl32(x1, 6); x1^=x0;
  x0+=ks2; x1+=k0+5u;
  o0 = x0; o1 = x1;
}

__device__ __forceinline__ uint2 mkk(uint32_t a, uint32_t b){ uint2 r; r.x=a; r.y=b; return r; }

// split(key, n)[i]  (partitionable)
__device__ __forceinline__ uint2 p_split(uint2 k, uint32_t i){
  uint32_t o0,o1; tf2(k.x,k.y,0u,i,o0,o1); return mkk(o0,o1);
}
// random_bits(key, 32, shape)[flat i]  (partitionable)
__device__ __forceinline__ uint32_t p_bits(uint2 k, uint32_t i){
  uint32_t o0,o1; tf2(k.x,k.y,0u,i,o0,o1); return o0^o1;
}

__device__ __forceinline__ float u01(uint32_t bits){
  return __uint_as_float((bits >> 9) | 0x3f800000u) - 1.0f;
}

// XLA ErfInv32 (Giles polynomials) — exact path, used by wood path
__device__ __forceinline__ float erfinv_f(float x){
  float w = -log1pf(-x*x);
  float p;
  if (w < 5.0f){
    w -= 2.5f;
    p = 2.81022636e-08f;
    p = fmaf(p,w, 3.43273939e-07f);
    p = fmaf(p,w,-3.5233877e-06f);
    p = fmaf(p,w,-4.39150654e-06f);
    p = fmaf(p,w, 0.00021858087f);
    p = fmaf(p,w,-0.00125372503f);
    p = fmaf(p,w,-0.00417768164f);
    p = fmaf(p,w, 0.246640727f);
    p = fmaf(p,w, 1.50140941f);
  } else {
    w = sqrtf(w) - 3.0f;
    p = -0.000200214257f;
    p = fmaf(p,w, 0.000100950558f);
    p = fmaf(p,w, 0.00134934322f);
    p = fmaf(p,w,-0.00367342844f);
    p = fmaf(p,w, 0.00573950773f);
    p = fmaf(p,w,-0.0076224613f);
    p = fmaf(p,w, 0.00943887047f);
    p = fmaf(p,w, 1.00167406f);
    p = fmaf(p,w, 2.83297682f);
  }
  return p * x;
}

// Fast normal for vec (hardware log2/sqrt; branch-free wrt accept/reject)
__device__ __forceinline__ float jnorm_fast(uint32_t bits){
  const float lo = -0.99999994f;
  float f = u01(bits);
  float x = fmaxf(lo, f*2.0f + lo);
  float w = -0.69314718f * __builtin_amdgcn_logf(fmaf(-x, x, 1.0f));
  float p;
  if (w < 5.0f){
    w -= 2.5f;
    p = 2.81022636e-08f;
    p = fmaf(p,w, 3.43273939e-07f);
    p = fmaf(p,w,-3.5233877e-06f);
    p = fmaf(p,w,-4.39150654e-06f);
    p = fmaf(p,w, 0.00021858087f);
    p = fmaf(p,w,-0.00125372503f);
    p = fmaf(p,w,-0.00417768164f);
    p = fmaf(p,w, 0.246640727f);
    p = fmaf(p,w, 1.50140941f);
  } else {
    w = __builtin_amdgcn_sqrtf(w) - 3.0f;
    p = -0.000200214257f;
    p = fmaf(p,w, 0.000100950558f);
    p = fmaf(p,w, 0.00134934322f);
    p = fmaf(p,w,-0.00367342844f);
    p = fmaf(p,w, 0.00573950773f);
    p = fmaf(p,w,-0.0076224613f);
    p = fmaf(p,w, 0.00943887047f);
    p = fmaf(p,w, 1.00167406f);
    p = fmaf(p,w, 2.83297682f);
  }
  return 1.41421356f * (p * x);
}

// jax _gamma_one(key, 63.5, log_space=True)
__device__ float loggamma_a635(uint2 ek){
  const float dg = 63.5f - (1.0f/3.0f);
  const float cg = (1.0f/3.0f) / sqrtf(dg);
  uint2 key = p_split(ek, 0);
  float lg = 0.0f;
  for (int it=0; it<64; ++it){
    uint2 xk = p_split(key, 1);
    uint2 uk = p_split(key, 2);
    uint2 sub2 = p_split(xk, 1);
    float x = 1.41421356f * erfinv_f(fmaxf(-0.99999994f,
                u01(p_bits(sub2, 0))*2.0f + (-0.99999994f)));
    float v = 1.0f + x*cg;
    float X = x*x;
    float V = v*v*v;
    float U = u01(p_bits(uk, 0));
    bool rej = (U >= 1.0f - 0.0331f*(X*X)) &&
               (logf(U) >= 0.5f*X + dg*((1.0f - V) + logf(V)));
    if (!rej){ lg = logf(dg) + logf(V); break; }
    key = p_split(key, 0);
  }
  return lg;
}

// ---------------------------------------------------------------------------
// bprep: W [128 l][512 k] f32 -> Bhi/Blo f16, MFMA-fragment-swizzled.
__global__ __launch_bounds__(256) void bprep_kernel(const float* __restrict__ W,
                                                    unsigned short* __restrict__ Bhi,
                                                    unsigned short* __restrict__ Blo){
  int t = blockIdx.x*256 + threadIdx.x;     // 16384 threads, 4 k's each
  int l = t >> 7, k4 = t & 127;             // n = l, k = 4*k4
  int k0 = k4*4;
  float4 wv = *(const float4*)(W + (size_t)l*HID + k0);
  half4 h, lo;
  float b0 = (float)(_Float16)wv.x; h.x = (_Float16)wv.x; lo.x = (_Float16)((wv.x-b0)*2048.0f);
  float b1 = (float)(_Float16)wv.y; h.y = (_Float16)wv.y; lo.y = (_Float16)((wv.y-b1)*2048.0f);
  float b2 = (float)(_Float16)wv.z; h.z = (_Float16)wv.z; lo.z = (_Float16)((wv.z-b2)*2048.0f);
  float b3 = (float)(_Float16)wv.w; h.w = (_Float16)wv.w; lo.w = (_Float16)((wv.w-b3)*2048.0f);
  int c = k0 >> 5, g = (k0 & 31) >> 3, j0 = k0 & 7;
  int nf = l >> 4, n15 = l & 15;
  size_t idx = ((size_t)((c*8 + nf)*4 + g)*16 + n15)*8 + j0;
  *(half4*)(Bhi + idx) = h;
  *(half4*)(Blo + idx) = lo;
}

// ---------------------------------------------------------------------------
// fused mu|wood: even blockIdx -> mu tile (blockIdx>>1), odd -> wood tile.
// mu path: MFMA fp16x3 GEMM, M-tile 64, K-chunk 32, 4 waves x (64r x 32c).
// wood path: Wood's vMF rejection (exact XLA math — flips live here).
__global__ __launch_bounds__(256) void muwood_kernel(const float* __restrict__ lat,
                                                     const unsigned short* __restrict__ Bhi_g,
                                                     const unsigned short* __restrict__ Blo_g,
                                                     const float* __restrict__ bmu,
                                                     float* __restrict__ muo,
                                                     float* __restrict__ kldo,
                                                     float* __restrict__ rno,
                                                     float kldv,
                                                     float* __restrict__ wbuf,
                                                     float* __restrict__ nwnbuf,
                                                     uint2 kw, uint2 kn,
                                                     float onepb, float onemb,
                                                     float xf, float cf){
  __shared__ __align__(16) char smem[26624];
  const int tid = threadIdx.x;

  if (blockIdx.x & 1){
    // ---------------- wood path ----------------
    uint32_t j = (blockIdx.x >> 1)*256u + tid;
    nwnbuf[j] = 1.0f + u01(p_bits(kn, j));
    uint2 key = kw;
    float w = 0.0f;
    for (int it=0; it<64; ++it){
      uint2 kz = p_split(key, 1);
      uint2 ku = p_split(key, 2);
      uint2 ka = p_split(kz, 0);
      uint2 kb = p_split(kz, 1);
      float lga = loggamma_a635(p_split(ka, j));
      float lgb = loggamma_a635(p_split(kb, j));
      float mx  = fmaxf(lga, lgb);
      float lab = mx + log1pf(expf(-fabsf(lga-lgb)));
      float z   = expf(lga - lab);
      float wn  = (1.0f - onepb*z) / (1.0f - onemb*z);
      float u   = u01(p_bits(ku, j));
      bool ok = (50.0f*wn + 127.0f*logf(1.0f - xf*wn) - cf) >= logf(u);
      if (ok){ w = wn; break; }
      key = p_split(key, 0);
    }
    wbuf[j] = w;
    return;
  }

  // ---------------- mu path ----------------
  _Float16* Ahi = (_Float16*)smem;                 // 64*40
  _Float16* Alo = (_Float16*)(smem + 5120);        // 64*40
  _Float16* Blh = (_Float16*)(smem + 10240);       // 4096
  _Float16* Bll = (_Float16*)(smem + 18432);       // 4096

  const int w   = tid >> 6;         // wave 0..3 -> cols w*32..+31
  const int lane = tid & 63;
  const int q = lane >> 4, n15 = lane & 15;
  const int b0 = (blockIdx.x >> 1) * 64;
  const float4* latg = (const float4*)lat;   // row stride 128 float4

  f32x4 acc1a[4][2], acc1b[4][2], acc2[4][2];
  #pragma unroll
  for (int rf=0;rf<4;++rf)
    #pragma unroll
    for (int nl=0;nl<2;++nl){
      acc1a[rf][nl] = (f32x4)0.0f;
      acc1b[rf][nl] = (f32x4)0.0f;
      acc2[rf][nl]  = (f32x4)0.0f;
    }

  for (int c=0;c<16;++c){
    __syncthreads();
    #pragma unroll
    for (int p=0;p<2;++p){
      int flat = p*256 + tid;          // 0..511
      int row = flat >> 3, k4 = flat & 7;   // k = c*32 + k4*4
      float4 lv = latg[(size_t)(b0+row)*(HID/4) + c*8 + k4];
      half4 h, lo;
      float r0=(float)(_Float16)lv.x; h.x=(_Float16)lv.x; lo.x=(_Float16)((lv.x-r0)*2048.0f);
      float r1=(float)(_Float16)lv.y; h.y=(_Float16)lv.y; lo.y=(_Float16)((lv.y-r1)*2048.0f);
      float r2=(float)(_Float16)lv.z; h.z=(_Float16)lv.z; lo.z=(_Float16)((lv.z-r2)*2048.0f);
      float r3=(float)(_Float16)lv.w; h.w=(_Float16)lv.w; lo.w=(_Float16)((lv.w-r3)*2048.0f);
      *(half4*)(Ahi + row*40 + k4*4) = h;
      *(half4*)(Alo + row*40 + k4*4) = lo;
    }
    {
      const short4* sh = (const short4*)Bhi_g + (size_t)c*1024;
      const short4* sl = (const short4*)Blo_g + (size_t)c*1024;
      short4* dh = (short4*)Blh;
      short4* dl = (short4*)Bll;
      #pragma unroll
      for (int p=0;p<4;++p){
        dh[tid + p*256] = sh[tid + p*256];
        dl[tid + p*256] = sl[tid + p*256];
      }
    }
    __syncthreads();

    half8 bh[2], bl[2];
    #pragma unroll
    for (int nl=0;nl<2;++nl){
      int nf = w*2 + nl;
      bh[nl] = *(const half8*)(Blh + ((nf*4 + q)*16 + n15)*8);
      bl[nl] = *(const half8*)(Bll + ((nf*4 + q)*16 + n15)*8);
    }
    #pragma unroll
    for (int rf=0;rf<4;++rf){
      half8 ah = *(const half8*)(Ahi + (rf*16 + n15)*40 + q*8);
      half8 al = *(const half8*)(Alo + (rf*16 + n15)*40 + q*8);
      #pragma unroll
      for (int nl=0;nl<2;++nl){
        if (c < 8)
          acc1a[rf][nl] = __builtin_amdgcn_mfma_f32_16x16x32_f16(ah, bh[nl], acc1a[rf][nl], 0,0,0);
        else
          acc1b[rf][nl] = __builtin_amdgcn_mfma_f32_16x16x32_f16(ah, bh[nl], acc1b[rf][nl], 0,0,0);
        acc2[rf][nl] = __builtin_amdgcn_mfma_f32_16x16x32_f16(ah, bl[nl], acc2[rf][nl], 0,0,0);
        acc2[rf][nl] = __builtin_amdgcn_mfma_f32_16x16x32_f16(al, bh[nl], acc2[rf][nl], 0,0,0);
      }
    }
  }

  // ---- epilogue: combine in f64, norm per row, outputs ----
  __syncthreads();
  double* nbuf  = (double*)smem;          // [4][64]
  double* normd = (double*)(smem + 2048); // [64]

  double bias[2];
  #pragma unroll
  for (int nl=0;nl<2;++nl) bias[nl] = (double)bmu[w*32 + nl*16 + n15];

  double val[4][2][4];
  double part[4][4];
  #pragma unroll
  for (int rf=0;rf<4;++rf){
    #pragma unroll
    for (int r=0;r<4;++r){
      double s = 0.0;
      #pragma unroll
      for (int nl=0;nl<2;++nl){
        double v = (double)acc1a[rf][nl][r] + (double)acc1b[rf][nl][r]
                 + (double)acc2[rf][nl][r]*(1.0/2048.0) + bias[nl];
        val[rf][nl][r] = v;
        s += v*v;
      }
      part[rf][r] = s;
    }
  }
  #pragma unroll
  for (int rf=0;rf<4;++rf)
    #pragma unroll
    for (int r=0;r<4;++r){
      double t = part[rf][r];
      t += __shfl_xor(t, 1, 64);
      t += __shfl_xor(t, 2, 64);
      t += __shfl_xor(t, 4, 64);
      t += __shfl_xor(t, 8, 64);
      part[rf][r] = t;
    }
  if (n15 == 0){
    #pragma unroll
    for (int rf=0;rf<4;++rf)
      #pragma unroll
      for (int r=0;r<4;++r)
        nbuf[w*64 + rf*16 + q*4 + r] = part[rf][r];
  }
  __syncthreads();
  if (tid < 64){
    double tot = nbuf[tid] + nbuf[64+tid] + nbuf[128+tid] + nbuf[192+tid];
    double nd = sqrt(tot);
    normd[tid] = nd;
    double om = 1.0 - nd;
    rno[b0 + tid]  = (float)(om*om);
    kldo[b0 + tid] = kldv;
  }
  __syncthreads();
  #pragma unroll
  for (int rf=0;rf<4;++rf){
    #pragma unroll
    for (int r=0;r<4;++r){
      double nd = normd[rf*16 + q*4 + r];
      int m = b0 + rf*16 + q*4 + r;
      #pragma unroll
      for (int nl=0;nl<2;++nl)
        muo[(size_t)m*LATD + w*32 + nl*16 + n15] = (float)(val[rf][nl][r]/nd);
    }
  }
}

// ---------------------------------------------------------------------------
// vec_kernel: one wave per b; lane owns components 2l,2l+1 of all 4 samples.
// Butterfly: DPP adds for 1/2/4/8 (quad_perm, half_mirror, mirror), swizzle 16,
// bpermute 32. half/full mirror are xor4/xor8-equivalent AFTER stages 1,2
// equalize the 4-groups (i^7 == 7-i on 3 bits; low-bit diffs are no-ops).
template<int CTRL>
__device__ __forceinline__ float dpp_add(float x){
  int v = __builtin_amdgcn_update_dpp(0, __float_as_int(x), CTRL, 0xF, 0xF, true);
  return x + __int_as_float(v);
}

__global__ __launch_bounds__(256) void vec_kernel(const float* __restrict__ mu,
                                                  const float* __restrict__ wbuf,
                                                  const float* __restrict__ nwnbuf,
                                                  float* __restrict__ vecs,
                                                  uint2 kv){
  uint32_t gid  = blockIdx.x*256u + threadIdx.x;
  uint32_t b    = gid >> 6;
  uint32_t lane = gid & 63u;
  float2 m = ((const float2*)mu)[(size_t)b*64 + lane];
  float wv[4], nv[4];
  #pragma unroll
  for (int s=0;s<4;s++){ wv[s]=wbuf[(uint32_t)s*BTOT+b]; nv[s]=nwnbuf[(uint32_t)s*BTOT+b]; }

  float v[4][2];
  #pragma unroll
  for (int s=0;s<4;++s){
    uint32_t jj = ((uint32_t)s*BTOT + b)*128u + lane*2u;
    v[s][0] = jnorm_fast(p_bits(kv, jj));
    v[s][1] = jnorm_fast(p_bits(kv, jj+1u));
  }

  float red[8];
  #pragma unroll
  for (int s=0;s<4;s++){
    red[s]   = fmaf(m.x, v[s][0], m.y*v[s][1]);             // dot partial
    red[4+s] = fmaf(v[s][0], v[s][0], v[s][1]*v[s][1]);     // |v|^2 partial
  }
  #pragma unroll
  for (int i=0;i<8;++i) red[i] = dpp_add<0xB1>(red[i]);     // xor 1 (quad_perm)
  #pragma unroll
  for (int i=0;i<8;++i) red[i] = dpp_add<0x4E>(red[i]);     // xor 2 (quad_perm)
  #pragma unroll
  for (int i=0;i<8;++i) red[i] = dpp_add<0x141>(red[i]);    // ~xor 4 (half_mirror)
  #pragma unroll
  for (int i=0;i<8;++i) red[i] = dpp_add<0x140>(red[i]);    // ~xor 8 (mirror)
  #pragma unroll
  for (int i=0;i<8;++i)
    red[i] += __int_as_float(__builtin_amdgcn_ds_swizzle(
                 __float_as_int(red[i]), 0x401F));          // xor 16
  #pragma unroll
  for (int i=0;i<8;++i) red[i] += __shfl_xor(red[i], 32, 64);

  #pragma unroll
  for (int s=0;s<4;s++){
    float dot = red[s];
    float on2 = fmaf(-dot, dot, red[4+s]);                  // |v|^2 - dot^2
    float a   = __builtin_amdgcn_rsqf(on2)
              * __builtin_amdgcn_sqrtf(fmaf(-wv[s], wv[s], 1.0f));
    float mw  = wv[s];
    float f0 = fmaf(fmaf(-m.x, dot, v[s][0]), a, m.x*mw) * nv[s];
    float f1 = fmaf(fmaf(-m.y, dot, v[s][1]), a, m.y*mw) * nv[s];
    ((float2*)vecs)[((size_t)s*BTOT + b)*64 + lane] = make_float2(f0,f1);
  }
}

// ---- host: KLD constant via the reference's lgamma series ----
static double log_iv_host(double nu, double k){
  double logt[300];
  double mx = -1e300;
  for (int m=0;m<300;m++){
    double md = (double)m;
    double t = (2.0*md + nu)*std::log(k/2.0) - std::lgamma(md+1.0) - std::lgamma(md+nu+1.0);
    logt[m]=t; if (t>mx) mx=t;
  }
  double s=0.0;
  for (int m=0;m<300;m++) s += std::exp(logt[m]-mx);
  return mx + std::log(s);
}

extern "C" void kernel_launch(void* const* d_in, const int* in_sizes, int n_in,
                              void* d_out, int out_size, void* d_ws, size_t ws_size,
                              hipStream_t stream) {
  const float* lat = (const float*)d_in[0];
  const float* W   = (const float*)d_in[1];
  const float* bmu = (const float*)d_in[2];
  float* out  = (float*)d_out;
  float* vecs = out;
  float* kld  = out + (size_t)NSAMP*BTOT*LATD;
  float* mu   = kld + BTOT;
  float* rn   = mu + (size_t)BTOT*LATD;

  float* wbuf   = (float*)d_ws;
  float* nwnbuf = wbuf + NW;
  unsigned short* Bhi = (unsigned short*)(nwnbuf + NW);
  unsigned short* Blo = Bhi + HID*LATD;

  // key(1) = (0,1); kw,kv,kn = split(key,3)  [partitionable]
  uint32_t o0,o1;
  uint2 kw, kv, kn;
  tf2(0u,1u,0u,0u,o0,o1); kw.x=o0; kw.y=o1;
  tf2(0u,1u,0u,1u,o0,o1); kv.x=o0; kv.y=o1;
  tf2(0u,1u,0u,2u,o0,o1); kn.x=o0; kn.y=o1;

  // Wood constants
  const double dd=127.0, kp=50.0;
  double bb = dd/(std::sqrt(4.0*kp*kp+dd*dd)+2.0*kp);
  double xx = (1.0-bb)/(1.0+bb);
  double cc = kp*xx + dd*std::log(1.0-xx*xx);
  float onepb=(float)(1.0+bb), onemb=(float)(1.0-bb), xf=(float)xx, cf=(float)cc;

  // KLD constant
  double li64 = log_iv_host(64.0, 50.0);
  double li65 = log_iv_host(65.0, 50.0);
  double ratio = std::exp(li65 - li64);
  const double dK = 128.0;
  double kld_d = kp*((ratio + dK/(2.0*kp)) - dK/(2.0*kp))
               + dK*std::log(kp)/2.0 - li64
               - std::lgamma(dK/2.0+1.0) - dK*std::log(2.0)/2.0
               + std::log((2.0-0.0)/(1.0-0.0));
  float kldv = (float)kld_d;

  bprep_kernel<<<(HID*LATD/4)/256, 256, 0, stream>>>(W, Bhi, Blo);
  muwood_kernel<<<2048, 256, 0, stream>>>(lat, Bhi, Blo, bmu, mu, kld, rn, kldv,
                                          wbuf, nwnbuf, kw, kn, onepb, onemb, xf, cf);
  vec_kernel<<<(BTOT*64)/256, 256, 0, stream>>>(mu, wbuf, nwnbuf, vecs, kv);
}

// Round 9
// 187.148 us; speedup vs baseline: 1.0282x; 1.0282x over previous
//
#include <hip/hip_runtime.h>
#include <cmath>
#include <cstdint>

// ---------------------------------------------------------------------------
// unif_vMF: JAX Threefry-2x32 replication (PARTITIONABLE semantics).
// R9: revert R8's mu+wood fusion (it starved both paths: 15% occupancy,
//     124us vs 75us serial). Keep R8's vec DPP butterfly + alignbit rotl;
//     add v_permlane32_swap for the xor-32 stage (VALU, off the LDS pipe).
//
// Outputs (flat concat in d_out, all f32):
//   vecs [4*65536*128] | kld [65536] | mu [65536*128] | redundant_norm [65536]
// Workspace: w[262144] f32 | nwn[262144] f32 | Bhi[65536] f16 | Blo[65536] f16
// ---------------------------------------------------------------------------

#define BTOT 65536
#define NSAMP 4
#define HID 512
#define LATD 128
#define NW 262144u      /* NSAMP*BTOT */

typedef _Float16 half8 __attribute__((ext_vector_type(8)));
typedef _Float16 half4 __attribute__((ext_vector_type(4)));
typedef float f32x4 __attribute__((ext_vector_type(4)));

__host__ __device__ __forceinline__ uint32_t rotl32(uint32_t v, int r){
#if defined(__HIP_DEVICE_COMPILE__)
  return __builtin_amdgcn_alignbit(v, v, 32 - r);   // 1-op rotate
#else
  return (v << r) | (v >> (32 - r));
#endif
}

// Threefry-2x32, 20 rounds, JAX's schedule.
__host__ __device__ __forceinline__ void tf2(uint32_t k0, uint32_t k1,
                                             uint32_t x0, uint32_t x1,
                                             uint32_t& o0, uint32_t& o1){
  uint32_t ks2 = k0 ^ k1 ^ 0x1BD11BDAu;
  x0 += k0; x1 += k1;
  x0+=x1; x1=rotl32(x1,13); x1^=x0;
  x0+=x1; x1=rotl32(x1,15); x1^=x0;
  x0+=x1; x1=rotl32(x1,26); x1^=x0;
  x0+=x1; x1=rotl32(x1, 6); x1^=x0;
  x0+=k1; x1+=ks2+1u;
  x0+=x1; x1=rotl32(x1,17); x1^=x0;
  x0+=x1; x1=rotl32(x1,29); x1^=x0;
  x0+=x1; x1=rotl32(x1,16); x1^=x0;
  x0+=x1; x1=rotl32(x1,24); x1^=x0;
  x0+=ks2; x1+=k0+2u;
  x0+=x1; x1=rotl32(x1,13); x1^=x0;
  x0+=x1; x1=rotl32(x1,15); x1^=x0;
  x0+=x1; x1=rotl32(x1,26); x1^=x0;
  x0+=x1; x1=rotl32(x1, 6); x1^=x0;
  x0+=k0; x1+=k1+3u;
  x0+=x1; x1=rotl32(x1,17); x1^=x0;
  x0+=x1; x1=rotl32(x1,29); x1^=x0;
  x0+=x1; x1=rotl32(x1,16); x1^=x0;
  x0+=x1; x1=rotl32(x1,24); x1^=x0;
  x0+=k1; x1+=ks2+4u;
  x0+=x1; x1=rotl32(x1,13); x1^=x0;
  x0+=x1; x1=rotl32(x1,15); x1^=x0;
  x0+=x1; x1=rotl32(x1,26); x1^=x0;
  x0+=x1; x1=rotl32(x1, 6); x1^=x0;
  x0+=ks2; x1+=k0+5u;
  o0 = x0; o1 = x1;
}

__device__ __forceinline__ uint2 mkk(uint32_t a, uint32_t b){ uint2 r; r.x=a; r.y=b; return r; }

// split(key, n)[i]  (partitionable)
__device__ __forceinline__ uint2 p_split(uint2 k, uint32_t i){
  uint32_t o0,o1; tf2(k.x,k.y,0u,i,o0,o1); return mkk(o0,o1);
}
// random_bits(key, 32, shape)[flat i]  (partitionable)
__device__ __forceinline__ uint32_t p_bits(uint2 k, uint32_t i){
  uint32_t o0,o1; tf2(k.x,k.y,0u,i,o0,o1); return o0^o1;
}

__device__ __forceinline__ float u01(uint32_t bits){
  return __uint_as_float((bits >> 9) | 0x3f800000u) - 1.0f;
}

// XLA ErfInv32 (Giles polynomials) — exact path, used by wood path
__device__ __forceinline__ float erfinv_f(float x){
  float w = -log1pf(-x*x);
  float p;
  if (w < 5.0f){
    w -= 2.5f;
    p = 2.81022636e-08f;
    p = fmaf(p,w, 3.43273939e-07f);
    p = fmaf(p,w,-3.5233877e-06f);
    p = fmaf(p,w,-4.39150654e-06f);
    p = fmaf(p,w, 0.00021858087f);
    p = fmaf(p,w,-0.00125372503f);
    p = fmaf(p,w,-0.00417768164f);
    p = fmaf(p,w, 0.246640727f);
    p = fmaf(p,w, 1.50140941f);
  } else {
    w = sqrtf(w) - 3.0f;
    p = -0.000200214257f;
    p = fmaf(p,w, 0.000100950558f);
    p = fmaf(p,w, 0.00134934322f);
    p = fmaf(p,w,-0.00367342844f);
    p = fmaf(p,w, 0.00573950773f);
    p = fmaf(p,w,-0.0076224613f);
    p = fmaf(p,w, 0.00943887047f);
    p = fmaf(p,w, 1.00167406f);
    p = fmaf(p,w, 2.83297682f);
  }
  return p * x;
}

// Fast normal for vec (hardware log2/sqrt; branch-free wrt accept/reject)
__device__ __forceinline__ float jnorm_fast(uint32_t bits){
  const float lo = -0.99999994f;
  float f = u01(bits);
  float x = fmaxf(lo, f*2.0f + lo);
  float w = -0.69314718f * __builtin_amdgcn_logf(fmaf(-x, x, 1.0f));
  float p;
  if (w < 5.0f){
    w -= 2.5f;
    p = 2.81022636e-08f;
    p = fmaf(p,w, 3.43273939e-07f);
    p = fmaf(p,w,-3.5233877e-06f);
    p = fmaf(p,w,-4.39150654e-06f);
    p = fmaf(p,w, 0.00021858087f);
    p = fmaf(p,w,-0.00125372503f);
    p = fmaf(p,w,-0.00417768164f);
    p = fmaf(p,w, 0.246640727f);
    p = fmaf(p,w, 1.50140941f);
  } else {
    w = __builtin_amdgcn_sqrtf(w) - 3.0f;
    p = -0.000200214257f;
    p = fmaf(p,w, 0.000100950558f);
    p = fmaf(p,w, 0.00134934322f);
    p = fmaf(p,w,-0.00367342844f);
    p = fmaf(p,w, 0.00573950773f);
    p = fmaf(p,w,-0.0076224613f);
    p = fmaf(p,w, 0.00943887047f);
    p = fmaf(p,w, 1.00167406f);
    p = fmaf(p,w, 2.83297682f);
  }
  return 1.41421356f * (p * x);
}

// jax _gamma_one(key, 63.5, log_space=True)
__device__ float loggamma_a635(uint2 ek){
  const float dg = 63.5f - (1.0f/3.0f);
  const float cg = (1.0f/3.0f) / sqrtf(dg);
  uint2 key = p_split(ek, 0);
  float lg = 0.0f;
  for (int it=0; it<64; ++it){
    uint2 xk = p_split(key, 1);
    uint2 uk = p_split(key, 2);
    uint2 sub2 = p_split(xk, 1);
    float x = 1.41421356f * erfinv_f(fmaxf(-0.99999994f,
                u01(p_bits(sub2, 0))*2.0f + (-0.99999994f)));
    float v = 1.0f + x*cg;
    float X = x*x;
    float V = v*v*v;
    float U = u01(p_bits(uk, 0));
    bool rej = (U >= 1.0f - 0.0331f*(X*X)) &&
               (logf(U) >= 0.5f*X + dg*((1.0f - V) + logf(V)));
    if (!rej){ lg = logf(dg) + logf(V); break; }
    key = p_split(key, 0);
  }
  return lg;
}

// ---------------------------------------------------------------------------
// bprep: W [128 l][512 k] f32 -> Bhi/Blo f16, MFMA-fragment-swizzled.
__global__ __launch_bounds__(256) void bprep_kernel(const float* __restrict__ W,
                                                    unsigned short* __restrict__ Bhi,
                                                    unsigned short* __restrict__ Blo){
  int t = blockIdx.x*256 + threadIdx.x;     // 16384 threads, 4 k's each
  int l = t >> 7, k4 = t & 127;             // n = l, k = 4*k4
  int k0 = k4*4;
  float4 wv = *(const float4*)(W + (size_t)l*HID + k0);
  half4 h, lo;
  float b0 = (float)(_Float16)wv.x; h.x = (_Float16)wv.x; lo.x = (_Float16)((wv.x-b0)*2048.0f);
  float b1 = (float)(_Float16)wv.y; h.y = (_Float16)wv.y; lo.y = (_Float16)((wv.y-b1)*2048.0f);
  float b2 = (float)(_Float16)wv.z; h.z = (_Float16)wv.z; lo.z = (_Float16)((wv.z-b2)*2048.0f);
  float b3 = (float)(_Float16)wv.w; h.w = (_Float16)wv.w; lo.w = (_Float16)((wv.w-b3)*2048.0f);
  int c = k0 >> 5, g = (k0 & 31) >> 3, j0 = k0 & 7;
  int nf = l >> 4, n15 = l & 15;
  size_t idx = ((size_t)((c*8 + nf)*4 + g)*16 + n15)*8 + j0;
  *(half4*)(Bhi + idx) = h;
  *(half4*)(Blo + idx) = lo;
}

// ---------------------------------------------------------------------------
// mu_kernel: MFMA fp16x3 GEMM, M-tile 64, K-chunk 32, 4 waves x (64r x 32c).
__global__ __launch_bounds__(256) void mu_kernel(const float* __restrict__ lat,
                                                 const unsigned short* __restrict__ Bhi_g,
                                                 const unsigned short* __restrict__ Blo_g,
                                                 const float* __restrict__ bmu,
                                                 float* __restrict__ muo,
                                                 float* __restrict__ kldo,
                                                 float* __restrict__ rno,
                                                 float kldv){
  __shared__ __align__(16) char smem[26624];
  _Float16* Ahi = (_Float16*)smem;                 // 64*40
  _Float16* Alo = (_Float16*)(smem + 5120);        // 64*40
  _Float16* Blh = (_Float16*)(smem + 10240);       // 4096
  _Float16* Bll = (_Float16*)(smem + 18432);       // 4096

  const int tid = threadIdx.x;
  const int w   = tid >> 6;         // wave 0..3 -> cols w*32..+31
  const int lane = tid & 63;
  const int q = lane >> 4, n15 = lane & 15;
  const int b0 = blockIdx.x * 64;
  const float4* latg = (const float4*)lat;   // row stride 128 float4

  f32x4 acc1a[4][2], acc1b[4][2], acc2[4][2];
  #pragma unroll
  for (int rf=0;rf<4;++rf)
    #pragma unroll
    for (int nl=0;nl<2;++nl){
      acc1a[rf][nl] = (f32x4)0.0f;
      acc1b[rf][nl] = (f32x4)0.0f;
      acc2[rf][nl]  = (f32x4)0.0f;
    }

  for (int c=0;c<16;++c){
    __syncthreads();
    #pragma unroll
    for (int p=0;p<2;++p){
      int flat = p*256 + tid;          // 0..511
      int row = flat >> 3, k4 = flat & 7;   // k = c*32 + k4*4
      float4 lv = latg[(size_t)(b0+row)*(HID/4) + c*8 + k4];
      half4 h, lo;
      float r0=(float)(_Float16)lv.x; h.x=(_Float16)lv.x; lo.x=(_Float16)((lv.x-r0)*2048.0f);
      float r1=(float)(_Float16)lv.y; h.y=(_Float16)lv.y; lo.y=(_Float16)((lv.y-r1)*2048.0f);
      float r2=(float)(_Float16)lv.z; h.z=(_Float16)lv.z; lo.z=(_Float16)((lv.z-r2)*2048.0f);
      float r3=(float)(_Float16)lv.w; h.w=(_Float16)lv.w; lo.w=(_Float16)((lv.w-r3)*2048.0f);
      *(half4*)(Ahi + row*40 + k4*4) = h;
      *(half4*)(Alo + row*40 + k4*4) = lo;
    }
    {
      const short4* sh = (const short4*)Bhi_g + (size_t)c*1024;
      const short4* sl = (const short4*)Blo_g + (size_t)c*1024;
      short4* dh = (short4*)Blh;
      short4* dl = (short4*)Bll;
      #pragma unroll
      for (int p=0;p<4;++p){
        dh[tid + p*256] = sh[tid + p*256];
        dl[tid + p*256] = sl[tid + p*256];
      }
    }
    __syncthreads();

    half8 bh[2], bl[2];
    #pragma unroll
    for (int nl=0;nl<2;++nl){
      int nf = w*2 + nl;
      bh[nl] = *(const half8*)(Blh + ((nf*4 + q)*16 + n15)*8);
      bl[nl] = *(const half8*)(Bll + ((nf*4 + q)*16 + n15)*8);
    }
    #pragma unroll
    for (int rf=0;rf<4;++rf){
      half8 ah = *(const half8*)(Ahi + (rf*16 + n15)*40 + q*8);
      half8 al = *(const half8*)(Alo + (rf*16 + n15)*40 + q*8);
      #pragma unroll
      for (int nl=0;nl<2;++nl){
        if (c < 8)
          acc1a[rf][nl] = __builtin_amdgcn_mfma_f32_16x16x32_f16(ah, bh[nl], acc1a[rf][nl], 0,0,0);
        else
          acc1b[rf][nl] = __builtin_amdgcn_mfma_f32_16x16x32_f16(ah, bh[nl], acc1b[rf][nl], 0,0,0);
        acc2[rf][nl] = __builtin_amdgcn_mfma_f32_16x16x32_f16(ah, bl[nl], acc2[rf][nl], 0,0,0);
        acc2[rf][nl] = __builtin_amdgcn_mfma_f32_16x16x32_f16(al, bh[nl], acc2[rf][nl], 0,0,0);
      }
    }
  }

  // ---- epilogue: combine in f64, norm per row, outputs ----
  __syncthreads();
  double* nbuf  = (double*)smem;          // [4][64]
  double* normd = (double*)(smem + 2048); // [64]

  double bias[2];
  #pragma unroll
  for (int nl=0;nl<2;++nl) bias[nl] = (double)bmu[w*32 + nl*16 + n15];

  double val[4][2][4];
  double part[4][4];
  #pragma unroll
  for (int rf=0;rf<4;++rf){
    #pragma unroll
    for (int r=0;r<4;++r){
      double s = 0.0;
      #pragma unroll
      for (int nl=0;nl<2;++nl){
        double v = (double)acc1a[rf][nl][r] + (double)acc1b[rf][nl][r]
                 + (double)acc2[rf][nl][r]*(1.0/2048.0) + bias[nl];
        val[rf][nl][r] = v;
        s += v*v;
      }
      part[rf][r] = s;
    }
  }
  #pragma unroll
  for (int rf=0;rf<4;++rf)
    #pragma unroll
    for (int r=0;r<4;++r){
      double t = part[rf][r];
      t += __shfl_xor(t, 1, 64);
      t += __shfl_xor(t, 2, 64);
      t += __shfl_xor(t, 4, 64);
      t += __shfl_xor(t, 8, 64);
      part[rf][r] = t;
    }
  if (n15 == 0){
    #pragma unroll
    for (int rf=0;rf<4;++rf)
      #pragma unroll
      for (int r=0;r<4;++r)
        nbuf[w*64 + rf*16 + q*4 + r] = part[rf][r];
  }
  __syncthreads();
  if (tid < 64){
    double tot = nbuf[tid] + nbuf[64+tid] + nbuf[128+tid] + nbuf[192+tid];
    double nd = sqrt(tot);
    normd[tid] = nd;
    double om = 1.0 - nd;
    rno[b0 + tid]  = (float)(om*om);
    kldo[b0 + tid] = kldv;
  }
  __syncthreads();
  #pragma unroll
  for (int rf=0;rf<4;++rf){
    #pragma unroll
    for (int r=0;r<4;++r){
      double nd = normd[rf*16 + q*4 + r];
      int m = b0 + rf*16 + q*4 + r;
      #pragma unroll
      for (int nl=0;nl<2;++nl)
        muo[(size_t)m*LATD + w*32 + nl*16 + n15] = (float)(val[rf][nl][r]/nd);
    }
  }
}

// Wood's vMF rejection for w[s][b] + noise (exact XLA math — flips live here)
__global__ __launch_bounds__(256) void wood_kernel(float* __restrict__ wbuf,
                                                   float* __restrict__ nwnbuf,
                                                   uint2 kw, uint2 kn,
                                                   float onepb, float onemb,
                                                   float xf, float cf){
  uint32_t j = blockIdx.x*256u + threadIdx.x;
  nwnbuf[j] = 1.0f + u01(p_bits(kn, j));
  uint2 key = kw;
  float w = 0.0f;
  for (int it=0; it<64; ++it){
    uint2 kz = p_split(key, 1);
    uint2 ku = p_split(key, 2);
    uint2 ka = p_split(kz, 0);
    uint2 kb = p_split(kz, 1);
    float lga = loggamma_a635(p_split(ka, j));
    float lgb = loggamma_a635(p_split(kb, j));
    float mx  = fmaxf(lga, lgb);
    float lab = mx + log1pf(expf(-fabsf(lga-lgb)));
    float z   = expf(lga - lab);
    float wn  = (1.0f - onepb*z) / (1.0f - onemb*z);
    float u   = u01(p_bits(ku, j));
    bool ok = (50.0f*wn + 127.0f*logf(1.0f - xf*wn) - cf) >= logf(u);
    if (ok){ w = wn; break; }
    key = p_split(key, 0);
  }
  wbuf[j] = w;
}

// ---------------------------------------------------------------------------
// vec_kernel: one wave per b; lane owns components 2l,2l+1 of all 4 samples.
// Butterfly: DPP adds for 1/2/4/8, swizzle for 16, v_permlane32_swap for 32
// (VALU pipe; (a',b')=swap(x,x) then a'+b' = x[l]+x[l^32], bit-identical).
template<int CTRL>
__device__ __forceinline__ float dpp_add(float x){
  int v = __builtin_amdgcn_update_dpp(0, __float_as_int(x), CTRL, 0xF, 0xF, true);
  return x + __int_as_float(v);
}

__device__ __forceinline__ float xor32_add(float x){
  int a = __float_as_int(x), b = __float_as_int(x);
  asm volatile("v_permlane32_swap_b32 %0, %1" : "+v"(a), "+v"(b));
  return __int_as_float(a) + __int_as_float(b);
}

__global__ __launch_bounds__(256) void vec_kernel(const float* __restrict__ mu,
                                                  const float* __restrict__ wbuf,
                                                  const float* __restrict__ nwnbuf,
                                                  float* __restrict__ vecs,
                                                  uint2 kv){
  uint32_t gid  = blockIdx.x*256u + threadIdx.x;
  uint32_t b    = gid >> 6;
  uint32_t lane = gid & 63u;
  float2 m = ((const float2*)mu)[(size_t)b*64 + lane];
  float wv[4], nv[4];
  #pragma unroll
  for (int s=0;s<4;s++){ wv[s]=wbuf[(uint32_t)s*BTOT+b]; nv[s]=nwnbuf[(uint32_t)s*BTOT+b]; }

  float v[4][2];
  #pragma unroll
  for (int s=0;s<4;++s){
    uint32_t jj = ((uint32_t)s*BTOT + b)*128u + lane*2u;
    v[s][0] = jnorm_fast(p_bits(kv, jj));
    v[s][1] = jnorm_fast(p_bits(kv, jj+1u));
  }

  float red[8];
  #pragma unroll
  for (int s=0;s<4;s++){
    red[s]   = fmaf(m.x, v[s][0], m.y*v[s][1]);             // dot partial
    red[4+s] = fmaf(v[s][0], v[s][0], v[s][1]*v[s][1]);     // |v|^2 partial
  }
  #pragma unroll
  for (int i=0;i<8;++i) red[i] = dpp_add<0xB1>(red[i]);     // xor 1 (quad_perm)
  #pragma unroll
  for (int i=0;i<8;++i) red[i] = dpp_add<0x4E>(red[i]);     // xor 2 (quad_perm)
  #pragma unroll
  for (int i=0;i<8;++i) red[i] = dpp_add<0x141>(red[i]);    // ~xor 4 (half_mirror)
  #pragma unroll
  for (int i=0;i<8;++i) red[i] = dpp_add<0x140>(red[i]);    // ~xor 8 (mirror)
  #pragma unroll
  for (int i=0;i<8;++i)
    red[i] += __int_as_float(__builtin_amdgcn_ds_swizzle(
                 __float_as_int(red[i]), 0x401F));          // xor 16
  #pragma unroll
  for (int i=0;i<8;++i) red[i] = xor32_add(red[i]);         // xor 32 (permlane)

  #pragma unroll
  for (int s=0;s<4;s++){
    float dot = red[s];
    float on2 = fmaf(-dot, dot, red[4+s]);                  // |v|^2 - dot^2
    float a   = __builtin_amdgcn_rsqf(on2)
              * __builtin_amdgcn_sqrtf(fmaf(-wv[s], wv[s], 1.0f));
    float mw  = wv[s];
    float f0 = fmaf(fmaf(-m.x, dot, v[s][0]), a, m.x*mw) * nv[s];
    float f1 = fmaf(fmaf(-m.y, dot, v[s][1]), a, m.y*mw) * nv[s];
    ((float2*)vecs)[((size_t)s*BTOT + b)*64 + lane] = make_float2(f0,f1);
  }
}

// ---- host: KLD constant via the reference's lgamma series ----
static double log_iv_host(double nu, double k){
  double logt[300];
  double mx = -1e300;
  for (int m=0;m<300;m++){
    double md = (double)m;
    double t = (2.0*md + nu)*std::log(k/2.0) - std::lgamma(md+1.0) - std::lgamma(md+nu+1.0);
    logt[m]=t; if (t>mx) mx=t;
  }
  double s=0.0;
  for (int m=0;m<300;m++) s += std::exp(logt[m]-mx);
  return mx + std::log(s);
}

extern "C" void kernel_launch(void* const* d_in, const int* in_sizes, int n_in,
                              void* d_out, int out_size, void* d_ws, size_t ws_size,
                              hipStream_t stream) {
  const float* lat = (const float*)d_in[0];
  const float* W   = (const float*)d_in[1];
  const float* bmu = (const float*)d_in[2];
  float* out  = (float*)d_out;
  float* vecs = out;
  float* kld  = out + (size_t)NSAMP*BTOT*LATD;
  float* mu   = kld + BTOT;
  float* rn   = mu + (size_t)BTOT*LATD;

  float* wbuf   = (float*)d_ws;
  float* nwnbuf = wbuf + NW;
  unsigned short* Bhi = (unsigned short*)(nwnbuf + NW);
  unsigned short* Blo = Bhi + HID*LATD;

  // key(1) = (0,1); kw,kv,kn = split(key,3)  [partitionable]
  uint32_t o0,o1;
  uint2 kw, kv, kn;
  tf2(0u,1u,0u,0u,o0,o1); kw.x=o0; kw.y=o1;
  tf2(0u,1u,0u,1u,o0,o1); kv.x=o0; kv.y=o1;
  tf2(0u,1u,0u,2u,o0,o1); kn.x=o0; kn.y=o1;

  // Wood constants
  const double dd=127.0, kp=50.0;
  double bb = dd/(std::sqrt(4.0*kp*kp+dd*dd)+2.0*kp);
  double xx = (1.0-bb)/(1.0+bb);
  double cc = kp*xx + dd*std::log(1.0-xx*xx);
  float onepb=(float)(1.0+bb), onemb=(float)(1.0-bb), xf=(float)xx, cf=(float)cc;

  // KLD constant
  double li64 = log_iv_host(64.0, 50.0);
  double li65 = log_iv_host(65.0, 50.0);
  double ratio = std::exp(li65 - li64);
  const double dK = 128.0;
  double kld_d = kp*((ratio + dK/(2.0*kp)) - dK/(2.0*kp))
               + dK*std::log(kp)/2.0 - li64
               - std::lgamma(dK/2.0+1.0) - dK*std::log(2.0)/2.0
               + std::log((2.0-0.0)/(1.0-0.0));
  float kldv = (float)kld_d;

  bprep_kernel<<<(HID*LATD/4)/256, 256, 0, stream>>>(W, Bhi, Blo);
  wood_kernel<<<NW/256, 256, 0, stream>>>(wbuf, nwnbuf, kw, kn, onepb, onemb, xf, cf);
  mu_kernel<<<BTOT/64, 256, 0, stream>>>(lat, Bhi, Blo, bmu, mu, kld, rn, kldv);
  vec_kernel<<<(BTOT*64)/256, 256, 0, stream>>>(mu, wbuf, nwnbuf, vecs, kv);
}

// Round 10
// 185.758 us; speedup vs baseline: 1.0359x; 1.0075x over previous
//
#include <hip/hip_runtime.h>
#include <cmath>
#include <cstdint>

// ---------------------------------------------------------------------------
// unif_vMF: JAX Threefry-2x32 replication (PARTITIONABLE semantics).
// R10: revert R9's permlane xor-32 (asm volatile serialized the 8 reduction
//      chains: vec ~64 -> ~107us). Back to __shfl_xor(.,32). Keep: unfused
//      kernels, DPP butterfly stages 1/2/4/8, swizzle-16, alignbit rotl.
//
// Outputs (flat concat in d_out, all f32):
//   vecs [4*65536*128] | kld [65536] | mu [65536*128] | redundant_norm [65536]
// Workspace: w[262144] f32 | nwn[262144] f32 | Bhi[65536] f16 | Blo[65536] f16
// ---------------------------------------------------------------------------

#define BTOT 65536
#define NSAMP 4
#define HID 512
#define LATD 128
#define NW 262144u      /* NSAMP*BTOT */

typedef _Float16 half8 __attribute__((ext_vector_type(8)));
typedef _Float16 half4 __attribute__((ext_vector_type(4)));
typedef float f32x4 __attribute__((ext_vector_type(4)));

__host__ __device__ __forceinline__ uint32_t rotl32(uint32_t v, int r){
#if defined(__HIP_DEVICE_COMPILE__)
  return __builtin_amdgcn_alignbit(v, v, 32 - r);   // 1-op rotate
#else
  return (v << r) | (v >> (32 - r));
#endif
}

// Threefry-2x32, 20 rounds, JAX's schedule.
__host__ __device__ __forceinline__ void tf2(uint32_t k0, uint32_t k1,
                                             uint32_t x0, uint32_t x1,
                                             uint32_t& o0, uint32_t& o1){
  uint32_t ks2 = k0 ^ k1 ^ 0x1BD11BDAu;
  x0 += k0; x1 += k1;
  x0+=x1; x1=rotl32(x1,13); x1^=x0;
  x0+=x1; x1=rotl32(x1,15); x1^=x0;
  x0+=x1; x1=rotl32(x1,26); x1^=x0;
  x0+=x1; x1=rotl32(x1, 6); x1^=x0;
  x0+=k1; x1+=ks2+1u;
  x0+=x1; x1=rotl32(x1,17); x1^=x0;
  x0+=x1; x1=rotl32(x1,29); x1^=x0;
  x0+=x1; x1=rotl32(x1,16); x1^=x0;
  x0+=x1; x1=rotl32(x1,24); x1^=x0;
  x0+=ks2; x1+=k0+2u;
  x0+=x1; x1=rotl32(x1,13); x1^=x0;
  x0+=x1; x1=rotl32(x1,15); x1^=x0;
  x0+=x1; x1=rotl32(x1,26); x1^=x0;
  x0+=x1; x1=rotl32(x1, 6); x1^=x0;
  x0+=k0; x1+=k1+3u;
  x0+=x1; x1=rotl32(x1,17); x1^=x0;
  x0+=x1; x1=rotl32(x1,29); x1^=x0;
  x0+=x1; x1=rotl32(x1,16); x1^=x0;
  x0+=x1; x1=rotl32(x1,24); x1^=x0;
  x0+=k1; x1+=ks2+4u;
  x0+=x1; x1=rotl32(x1,13); x1^=x0;
  x0+=x1; x1=rotl32(x1,15); x1^=x0;
  x0+=x1; x1=rotl32(x1,26); x1^=x0;
  x0+=x1; x1=rotl32(x1, 6); x1^=x0;
  x0+=ks2; x1+=k0+5u;
  o0 = x0; o1 = x1;
}

__device__ __forceinline__ uint2 mkk(uint32_t a, uint32_t b){ uint2 r; r.x=a; r.y=b; return r; }

// split(key, n)[i]  (partitionable)
__device__ __forceinline__ uint2 p_split(uint2 k, uint32_t i){
  uint32_t o0,o1; tf2(k.x,k.y,0u,i,o0,o1); return mkk(o0,o1);
}
// random_bits(key, 32, shape)[flat i]  (partitionable)
__device__ __forceinline__ uint32_t p_bits(uint2 k, uint32_t i){
  uint32_t o0,o1; tf2(k.x,k.y,0u,i,o0,o1); return o0^o1;
}

__device__ __forceinline__ float u01(uint32_t bits){
  return __uint_as_float((bits >> 9) | 0x3f800000u) - 1.0f;
}

// XLA ErfInv32 (Giles polynomials) — exact path, used by wood path
__device__ __forceinline__ float erfinv_f(float x){
  float w = -log1pf(-x*x);
  float p;
  if (w < 5.0f){
    w -= 2.5f;
    p = 2.81022636e-08f;
    p = fmaf(p,w, 3.43273939e-07f);
    p = fmaf(p,w,-3.5233877e-06f);
    p = fmaf(p,w,-4.39150654e-06f);
    p = fmaf(p,w, 0.00021858087f);
    p = fmaf(p,w,-0.00125372503f);
    p = fmaf(p,w,-0.00417768164f);
    p = fmaf(p,w, 0.246640727f);
    p = fmaf(p,w, 1.50140941f);
  } else {
    w = sqrtf(w) - 3.0f;
    p = -0.000200214257f;
    p = fmaf(p,w, 0.000100950558f);
    p = fmaf(p,w, 0.00134934322f);
    p = fmaf(p,w,-0.00367342844f);
    p = fmaf(p,w, 0.00573950773f);
    p = fmaf(p,w,-0.0076224613f);
    p = fmaf(p,w, 0.00943887047f);
    p = fmaf(p,w, 1.00167406f);
    p = fmaf(p,w, 2.83297682f);
  }
  return p * x;
}

// Fast normal for vec (hardware log2/sqrt; branch-free wrt accept/reject)
__device__ __forceinline__ float jnorm_fast(uint32_t bits){
  const float lo = -0.99999994f;
  float f = u01(bits);
  float x = fmaxf(lo, f*2.0f + lo);
  float w = -0.69314718f * __builtin_amdgcn_logf(fmaf(-x, x, 1.0f));
  float p;
  if (w < 5.0f){
    w -= 2.5f;
    p = 2.81022636e-08f;
    p = fmaf(p,w, 3.43273939e-07f);
    p = fmaf(p,w,-3.5233877e-06f);
    p = fmaf(p,w,-4.39150654e-06f);
    p = fmaf(p,w, 0.00021858087f);
    p = fmaf(p,w,-0.00125372503f);
    p = fmaf(p,w,-0.00417768164f);
    p = fmaf(p,w, 0.246640727f);
    p = fmaf(p,w, 1.50140941f);
  } else {
    w = __builtin_amdgcn_sqrtf(w) - 3.0f;
    p = -0.000200214257f;
    p = fmaf(p,w, 0.000100950558f);
    p = fmaf(p,w, 0.00134934322f);
    p = fmaf(p,w,-0.00367342844f);
    p = fmaf(p,w, 0.00573950773f);
    p = fmaf(p,w,-0.0076224613f);
    p = fmaf(p,w, 0.00943887047f);
    p = fmaf(p,w, 1.00167406f);
    p = fmaf(p,w, 2.83297682f);
  }
  return 1.41421356f * (p * x);
}

// jax _gamma_one(key, 63.5, log_space=True)
__device__ float loggamma_a635(uint2 ek){
  const float dg = 63.5f - (1.0f/3.0f);
  const float cg = (1.0f/3.0f) / sqrtf(dg);
  uint2 key = p_split(ek, 0);
  float lg = 0.0f;
  for (int it=0; it<64; ++it){
    uint2 xk = p_split(key, 1);
    uint2 uk = p_split(key, 2);
    uint2 sub2 = p_split(xk, 1);
    float x = 1.41421356f * erfinv_f(fmaxf(-0.99999994f,
                u01(p_bits(sub2, 0))*2.0f + (-0.99999994f)));
    float v = 1.0f + x*cg;
    float X = x*x;
    float V = v*v*v;
    float U = u01(p_bits(uk, 0));
    bool rej = (U >= 1.0f - 0.0331f*(X*X)) &&
               (logf(U) >= 0.5f*X + dg*((1.0f - V) + logf(V)));
    if (!rej){ lg = logf(dg) + logf(V); break; }
    key = p_split(key, 0);
  }
  return lg;
}

// ---------------------------------------------------------------------------
// bprep: W [128 l][512 k] f32 -> Bhi/Blo f16, MFMA-fragment-swizzled.
__global__ __launch_bounds__(256) void bprep_kernel(const float* __restrict__ W,
                                                    unsigned short* __restrict__ Bhi,
                                                    unsigned short* __restrict__ Blo){
  int t = blockIdx.x*256 + threadIdx.x;     // 16384 threads, 4 k's each
  int l = t >> 7, k4 = t & 127;             // n = l, k = 4*k4
  int k0 = k4*4;
  float4 wv = *(const float4*)(W + (size_t)l*HID + k0);
  half4 h, lo;
  float b0 = (float)(_Float16)wv.x; h.x = (_Float16)wv.x; lo.x = (_Float16)((wv.x-b0)*2048.0f);
  float b1 = (float)(_Float16)wv.y; h.y = (_Float16)wv.y; lo.y = (_Float16)((wv.y-b1)*2048.0f);
  float b2 = (float)(_Float16)wv.z; h.z = (_Float16)wv.z; lo.z = (_Float16)((wv.z-b2)*2048.0f);
  float b3 = (float)(_Float16)wv.w; h.w = (_Float16)wv.w; lo.w = (_Float16)((wv.w-b3)*2048.0f);
  int c = k0 >> 5, g = (k0 & 31) >> 3, j0 = k0 & 7;
  int nf = l >> 4, n15 = l & 15;
  size_t idx = ((size_t)((c*8 + nf)*4 + g)*16 + n15)*8 + j0;
  *(half4*)(Bhi + idx) = h;
  *(half4*)(Blo + idx) = lo;
}

// ---------------------------------------------------------------------------
// mu_kernel: MFMA fp16x3 GEMM, M-tile 64, K-chunk 32, 4 waves x (64r x 32c).
__global__ __launch_bounds__(256) void mu_kernel(const float* __restrict__ lat,
                                                 const unsigned short* __restrict__ Bhi_g,
                                                 const unsigned short* __restrict__ Blo_g,
                                                 const float* __restrict__ bmu,
                                                 float* __restrict__ muo,
                                                 float* __restrict__ kldo,
                                                 float* __restrict__ rno,
                                                 float kldv){
  __shared__ __align__(16) char smem[26624];
  _Float16* Ahi = (_Float16*)smem;                 // 64*40
  _Float16* Alo = (_Float16*)(smem + 5120);        // 64*40
  _Float16* Blh = (_Float16*)(smem + 10240);       // 4096
  _Float16* Bll = (_Float16*)(smem + 18432);       // 4096

  const int tid = threadIdx.x;
  const int w   = tid >> 6;         // wave 0..3 -> cols w*32..+31
  const int lane = tid & 63;
  const int q = lane >> 4, n15 = lane & 15;
  const int b0 = blockIdx.x * 64;
  const float4* latg = (const float4*)lat;   // row stride 128 float4

  f32x4 acc1a[4][2], acc1b[4][2], acc2[4][2];
  #pragma unroll
  for (int rf=0;rf<4;++rf)
    #pragma unroll
    for (int nl=0;nl<2;++nl){
      acc1a[rf][nl] = (f32x4)0.0f;
      acc1b[rf][nl] = (f32x4)0.0f;
      acc2[rf][nl]  = (f32x4)0.0f;
    }

  for (int c=0;c<16;++c){
    __syncthreads();
    #pragma unroll
    for (int p=0;p<2;++p){
      int flat = p*256 + tid;          // 0..511
      int row = flat >> 3, k4 = flat & 7;   // k = c*32 + k4*4
      float4 lv = latg[(size_t)(b0+row)*(HID/4) + c*8 + k4];
      half4 h, lo;
      float r0=(float)(_Float16)lv.x; h.x=(_Float16)lv.x; lo.x=(_Float16)((lv.x-r0)*2048.0f);
      float r1=(float)(_Float16)lv.y; h.y=(_Float16)lv.y; lo.y=(_Float16)((lv.y-r1)*2048.0f);
      float r2=(float)(_Float16)lv.z; h.z=(_Float16)lv.z; lo.z=(_Float16)((lv.z-r2)*2048.0f);
      float r3=(float)(_Float16)lv.w; h.w=(_Float16)lv.w; lo.w=(_Float16)((lv.w-r3)*2048.0f);
      *(half4*)(Ahi + row*40 + k4*4) = h;
      *(half4*)(Alo + row*40 + k4*4) = lo;
    }
    {
      const short4* sh = (const short4*)Bhi_g + (size_t)c*1024;
      const short4* sl = (const short4*)Blo_g + (size_t)c*1024;
      short4* dh = (short4*)Blh;
      short4* dl = (short4*)Bll;
      #pragma unroll
      for (int p=0;p<4;++p){
        dh[tid + p*256] = sh[tid + p*256];
        dl[tid + p*256] = sl[tid + p*256];
      }
    }
    __syncthreads();

    half8 bh[2], bl[2];
    #pragma unroll
    for (int nl=0;nl<2;++nl){
      int nf = w*2 + nl;
      bh[nl] = *(const half8*)(Blh + ((nf*4 + q)*16 + n15)*8);
      bl[nl] = *(const half8*)(Bll + ((nf*4 + q)*16 + n15)*8);
    }
    #pragma unroll
    for (int rf=0;rf<4;++rf){
      half8 ah = *(const half8*)(Ahi + (rf*16 + n15)*40 + q*8);
      half8 al = *(const half8*)(Alo + (rf*16 + n15)*40 + q*8);
      #pragma unroll
      for (int nl=0;nl<2;++nl){
        if (c < 8)
          acc1a[rf][nl] = __builtin_amdgcn_mfma_f32_16x16x32_f16(ah, bh[nl], acc1a[rf][nl], 0,0,0);
        else
          acc1b[rf][nl] = __builtin_amdgcn_mfma_f32_16x16x32_f16(ah, bh[nl], acc1b[rf][nl], 0,0,0);
        acc2[rf][nl] = __builtin_amdgcn_mfma_f32_16x16x32_f16(ah, bl[nl], acc2[rf][nl], 0,0,0);
        acc2[rf][nl] = __builtin_amdgcn_mfma_f32_16x16x32_f16(al, bh[nl], acc2[rf][nl], 0,0,0);
      }
    }
  }

  // ---- epilogue: combine in f64, norm per row, outputs ----
  __syncthreads();
  double* nbuf  = (double*)smem;          // [4][64]
  double* normd = (double*)(smem + 2048); // [64]

  double bias[2];
  #pragma unroll
  for (int nl=0;nl<2;++nl) bias[nl] = (double)bmu[w*32 + nl*16 + n15];

  double val[4][2][4];
  double part[4][4];
  #pragma unroll
  for (int rf=0;rf<4;++rf){
    #pragma unroll
    for (int r=0;r<4;++r){
      double s = 0.0;
      #pragma unroll
      for (int nl=0;nl<2;++nl){
        double v = (double)acc1a[rf][nl][r] + (double)acc1b[rf][nl][r]
                 + (double)acc2[rf][nl][r]*(1.0/2048.0) + bias[nl];
        val[rf][nl][r] = v;
        s += v*v;
      }
      part[rf][r] = s;
    }
  }
  #pragma unroll
  for (int rf=0;rf<4;++rf)
    #pragma unroll
    for (int r=0;r<4;++r){
      double t = part[rf][r];
      t += __shfl_xor(t, 1, 64);
      t += __shfl_xor(t, 2, 64);
      t += __shfl_xor(t, 4, 64);
      t += __shfl_xor(t, 8, 64);
      part[rf][r] = t;
    }
  if (n15 == 0){
    #pragma unroll
    for (int rf=0;rf<4;++rf)
      #pragma unroll
      for (int r=0;r<4;++r)
        nbuf[w*64 + rf*16 + q*4 + r] = part[rf][r];
  }
  __syncthreads();
  if (tid < 64){
    double tot = nbuf[tid] + nbuf[64+tid] + nbuf[128+tid] + nbuf[192+tid];
    double nd = sqrt(tot);
    normd[tid] = nd;
    double om = 1.0 - nd;
    rno[b0 + tid]  = (float)(om*om);
    kldo[b0 + tid] = kldv;
  }
  __syncthreads();
  #pragma unroll
  for (int rf=0;rf<4;++rf){
    #pragma unroll
    for (int r=0;r<4;++r){
      double nd = normd[rf*16 + q*4 + r];
      int m = b0 + rf*16 + q*4 + r;
      #pragma unroll
      for (int nl=0;nl<2;++nl)
        muo[(size_t)m*LATD + w*32 + nl*16 + n15] = (float)(val[rf][nl][r]/nd);
    }
  }
}

// Wood's vMF rejection for w[s][b] + noise (exact XLA math — flips live here)
__global__ __launch_bounds__(256) void wood_kernel(float* __restrict__ wbuf,
                                                   float* __restrict__ nwnbuf,
                                                   uint2 kw, uint2 kn,
                                                   float onepb, float onemb,
                                                   float xf, float cf){
  uint32_t j = blockIdx.x*256u + threadIdx.x;
  nwnbuf[j] = 1.0f + u01(p_bits(kn, j));
  uint2 key = kw;
  float w = 0.0f;
  for (int it=0; it<64; ++it){
    uint2 kz = p_split(key, 1);
    uint2 ku = p_split(key, 2);
    uint2 ka = p_split(kz, 0);
    uint2 kb = p_split(kz, 1);
    float lga = loggamma_a635(p_split(ka, j));
    float lgb = loggamma_a635(p_split(kb, j));
    float mx  = fmaxf(lga, lgb);
    float lab = mx + log1pf(expf(-fabsf(lga-lgb)));
    float z   = expf(lga - lab);
    float wn  = (1.0f - onepb*z) / (1.0f - onemb*z);
    float u   = u01(p_bits(ku, j));
    bool ok = (50.0f*wn + 127.0f*logf(1.0f - xf*wn) - cf) >= logf(u);
    if (ok){ w = wn; break; }
    key = p_split(key, 0);
  }
  wbuf[j] = w;
}

// ---------------------------------------------------------------------------
// vec_kernel: one wave per b; lane owns components 2l,2l+1 of all 4 samples.
// Butterfly: DPP adds for 1/2/4/8, swizzle for 16, __shfl_xor for 32.
template<int CTRL>
__device__ __forceinline__ float dpp_add(float x){
  int v = __builtin_amdgcn_update_dpp(0, __float_as_int(x), CTRL, 0xF, 0xF, true);
  return x + __int_as_float(v);
}

__global__ __launch_bounds__(256) void vec_kernel(const float* __restrict__ mu,
                                                  const float* __restrict__ wbuf,
                                                  const float* __restrict__ nwnbuf,
                                                  float* __restrict__ vecs,
                                                  uint2 kv){
  uint32_t gid  = blockIdx.x*256u + threadIdx.x;
  uint32_t b    = gid >> 6;
  uint32_t lane = gid & 63u;
  float2 m = ((const float2*)mu)[(size_t)b*64 + lane];
  float wv[4], nv[4];
  #pragma unroll
  for (int s=0;s<4;s++){ wv[s]=wbuf[(uint32_t)s*BTOT+b]; nv[s]=nwnbuf[(uint32_t)s*BTOT+b]; }

  float v[4][2];
  #pragma unroll
  for (int s=0;s<4;++s){
    uint32_t jj = ((uint32_t)s*BTOT + b)*128u + lane*2u;
    v[s][0] = jnorm_fast(p_bits(kv, jj));
    v[s][1] = jnorm_fast(p_bits(kv, jj+1u));
  }

  float red[8];
  #pragma unroll
  for (int s=0;s<4;s++){
    red[s]   = fmaf(m.x, v[s][0], m.y*v[s][1]);             // dot partial
    red[4+s] = fmaf(v[s][0], v[s][0], v[s][1]*v[s][1]);     // |v|^2 partial
  }
  #pragma unroll
  for (int i=0;i<8;++i) red[i] = dpp_add<0xB1>(red[i]);     // xor 1 (quad_perm)
  #pragma unroll
  for (int i=0;i<8;++i) red[i] = dpp_add<0x4E>(red[i]);     // xor 2 (quad_perm)
  #pragma unroll
  for (int i=0;i<8;++i) red[i] = dpp_add<0x141>(red[i]);    // ~xor 4 (half_mirror)
  #pragma unroll
  for (int i=0;i<8;++i) red[i] = dpp_add<0x140>(red[i]);    // ~xor 8 (mirror)
  #pragma unroll
  for (int i=0;i<8;++i)
    red[i] += __int_as_float(__builtin_amdgcn_ds_swizzle(
                 __float_as_int(red[i]), 0x401F));          // xor 16
  #pragma unroll
  for (int i=0;i<8;++i) red[i] += __shfl_xor(red[i], 32, 64);

  #pragma unroll
  for (int s=0;s<4;s++){
    float dot = red[s];
    float on2 = fmaf(-dot, dot, red[4+s]);                  // |v|^2 - dot^2
    float a   = __builtin_amdgcn_rsqf(on2)
              * __builtin_amdgcn_sqrtf(fmaf(-wv[s], wv[s], 1.0f));
    float mw  = wv[s];
    float f0 = fmaf(fmaf(-m.x, dot, v[s][0]), a, m.x*mw) * nv[s];
    float f1 = fmaf(fmaf(-m.y, dot, v[s][1]), a, m.y*mw) * nv[s];
    ((float2*)vecs)[((size_t)s*BTOT + b)*64 + lane] = make_float2(f0,f1);
  }
}

// ---- host: KLD constant via the reference's lgamma series ----
static double log_iv_host(double nu, double k){
  double logt[300];
  double mx = -1e300;
  for (int m=0;m<300;m++){
    double md = (double)m;
    double t = (2.0*md + nu)*std::log(k/2.0) - std::lgamma(md+1.0) - std::lgamma(md+nu+1.0);
    logt[m]=t; if (t>mx) mx=t;
  }
  double s=0.0;
  for (int m=0;m<300;m++) s += std::exp(logt[m]-mx);
  return mx + std::log(s);
}

extern "C" void kernel_launch(void* const* d_in, const int* in_sizes, int n_in,
                              void* d_out, int out_size, void* d_ws, size_t ws_size,
                              hipStream_t stream) {
  const float* lat = (const float*)d_in[0];
  const float* W   = (const float*)d_in[1];
  const float* bmu = (const float*)d_in[2];
  float* out  = (float*)d_out;
  float* vecs = out;
  float* kld  = out + (size_t)NSAMP*BTOT*LATD;
  float* mu   = kld + BTOT;
  float* rn   = mu + (size_t)BTOT*LATD;

  float* wbuf   = (float*)d_ws;
  float* nwnbuf = wbuf + NW;
  unsigned short* Bhi = (unsigned short*)(nwnbuf + NW);
  unsigned short* Blo = Bhi + HID*LATD;

  // key(1) = (0,1); kw,kv,kn = split(key,3)  [partitionable]
  uint32_t o0,o1;
  uint2 kw, kv, kn;
  tf2(0u,1u,0u,0u,o0,o1); kw.x=o0; kw.y=o1;
  tf2(0u,1u,0u,1u,o0,o1); kv.x=o0; kv.y=o1;
  tf2(0u,1u,0u,2u,o0,o1); kn.x=o0; kn.y=o1;

  // Wood constants
  const double dd=127.0, kp=50.0;
  double bb = dd/(std::sqrt(4.0*kp*kp+dd*dd)+2.0*kp);
  double xx = (1.0-bb)/(1.0+bb);
  double cc = kp*xx + dd*std::log(1.0-xx*xx);
  float onepb=(float)(1.0+bb), onemb=(float)(1.0-bb), xf=(float)xx, cf=(float)cc;

  // KLD constant
  double li64 = log_iv_host(64.0, 50.0);
  double li65 = log_iv_host(65.0, 50.0);
  double ratio = std::exp(li65 - li64);
  const double dK = 128.0;
  double kld_d = kp*((ratio + dK/(2.0*kp)) - dK/(2.0*kp))
               + dK*std::log(kp)/2.0 - li64
               - std::lgamma(dK/2.0+1.0) - dK*std::log(2.0)/2.0
               + std::log((2.0-0.0)/(1.0-0.0));
  float kldv = (float)kld_d;

  bprep_kernel<<<(HID*LATD/4)/256, 256, 0, stream>>>(W, Bhi, Blo);
  wood_kernel<<<NW/256, 256, 0, stream>>>(wbuf, nwnbuf, kw, kn, onepb, onemb, xf, cf);
  mu_kernel<<<BTOT/64, 256, 0, stream>>>(lat, Bhi, Blo, bmu, mu, kld, rn, kldv);
  vec_kernel<<<(BTOT*64)/256, 256, 0, stream>>>(mu, wbuf, nwnbuf, vecs, kv);
}